// Round 1
// baseline (656.509 us; speedup 1.0000x reference)
//
#include <hip/hip_runtime.h>
#include <hip/hip_bf16.h>
#include <stdint.h>

// Problem dims (fixed by reference)
#define TOKENS 8192
#define DIN    4096
#define DOUT   4096

typedef short bf16x8 __attribute__((ext_vector_type(8)));  // 8 bf16 = 4 VGPRs
typedef float f32x4  __attribute__((ext_vector_type(4)));  // MFMA 16x16 accum

// ---- fp32 -> bf16 round-to-nearest-even (inputs are finite; no NaN path) ----
__device__ __forceinline__ unsigned short f2bf(float f) {
    union { float f; unsigned int u; } v; v.f = f;
    return (unsigned short)((v.u + 0x7fffu + ((v.u >> 16) & 1u)) >> 16);
}

// ---- async global->LDS, 16B per lane; LDS dest = wave-uniform base + lane*16 ----
__device__ __forceinline__ void gload_lds16(const unsigned short* g, unsigned short* l) {
    __builtin_amdgcn_global_load_lds(
        (const __attribute__((address_space(1))) unsigned int*)g,
        (__attribute__((address_space(3))) unsigned int*)l,
        16, 0, 0);
}

// ================= prologue 1: x fp32 -> bf16 =================
__global__ void cvt_x_kernel(const float* __restrict__ x,
                             unsigned short* __restrict__ xb, int n4) {
    int i = blockIdx.x * blockDim.x + threadIdx.x;
    int stride = gridDim.x * blockDim.x;
    const float4* x4 = (const float4*)x;
    ushort4* o4 = (ushort4*)xb;
    for (; i < n4; i += stride) {
        float4 v = x4[i];
        ushort4 o;
        o.x = f2bf(v.x); o.y = f2bf(v.y); o.z = f2bf(v.z); o.w = f2bf(v.w);
        o4[i] = o;
    }
}

// ======= prologue 2: W int32 [K][N] -> Wt bf16 [N][K] (transpose) =======
__global__ void cvt_w_kernel(const int* __restrict__ W,
                             unsigned short* __restrict__ Wt) {
    __shared__ unsigned short tile[32][33];
    const int tx = threadIdx.x;          // 0..31
    const int ty = threadIdx.y;          // 0..7
    const int k0 = blockIdx.y * 32;
    const int n0 = blockIdx.x * 32;
#pragma unroll
    for (int i = 0; i < 32; i += 8) {
        int k = k0 + ty + i;
        tile[ty + i][tx] = f2bf((float)W[(size_t)k * DOUT + n0 + tx]);
    }
    __syncthreads();
#pragma unroll
    for (int i = 0; i < 32; i += 8) {
        int n = n0 + ty + i;
        Wt[(size_t)n * DIN + k0 + tx] = tile[tx][ty + i];
    }
}

// ================= main GEMM: C[M][N] = A[M][K] * Bt[N][K]^T =================
// m97 structure: 128x128 tile, BK=32, 4 waves 2x2, each wave 4x4 of 16x16x32 MFMA.
#define BM 128
#define BN 128
#define BK 32

__global__ __launch_bounds__(256) void gemm_bt(
    const unsigned short* __restrict__ A,   // [M][K] bf16
    const unsigned short* __restrict__ B,   // [N][K] bf16 (W transposed)
    float* __restrict__ C) {                // [M][N] fp32
    const int K = DIN, N = DOUT;

    __shared__ __align__(16) unsigned short sA[BM * BK];  // 8 KB
    __shared__ __align__(16) unsigned short sB[BN * BK];  // 8 KB

    const int wave = threadIdx.x >> 6;
    const int lane = threadIdx.x & 63;
    const int waveM = (wave >> 1) * 64;
    const int waveN = (wave & 1) * 64;

    const unsigned short* Ablk = A + (size_t)(blockIdx.y * BM) * K;
    const unsigned short* Bblk = B + (size_t)(blockIdx.x * BN) * K;

    // staging: each wave owns two 1KB chunks (16 rows x 64B each) of sA and sB
    const int c0   = wave * 2;
    const int srow = c0 * 16 + (lane >> 2);      // source row within tile
    const int kofs = (lane & 3) * 8;             // bf16 elems within BK row
    const unsigned short* gA0 = Ablk + (size_t)srow * K + kofs;
    const unsigned short* gA1 = gA0 + (size_t)16 * K;
    const unsigned short* gB0 = Bblk + (size_t)srow * K + kofs;
    const unsigned short* gB1 = gB0 + (size_t)16 * K;
    unsigned short* lA0 = &sA[c0 * 512];
    unsigned short* lA1 = &sA[(c0 + 1) * 512];
    unsigned short* lB0 = &sB[c0 * 512];
    unsigned short* lB1 = &sB[(c0 + 1) * 512];

    // fragment read indices (A-operand layout: lane -> [m=lane&15][k=(lane>>4)*8+j])
    const int mrow = lane & 15;
    const int kq   = (lane >> 4) * 8;

    f32x4 acc[4][4];
#pragma unroll
    for (int i = 0; i < 4; ++i)
#pragma unroll
        for (int j = 0; j < 4; ++j) {
            f32x4 z = {0.f, 0.f, 0.f, 0.f};
            acc[i][j] = z;
        }

    for (int kt = 0; kt < K; kt += BK) {
        __syncthreads();                      // prior reads done before overwrite
        gload_lds16(gA0 + kt, lA0);
        gload_lds16(gA1 + kt, lA1);
        gload_lds16(gB0 + kt, lB0);
        gload_lds16(gB1 + kt, lB1);
        __syncthreads();                      // drains vmcnt(0): staging visible

        bf16x8 af[4], bfr[4];
#pragma unroll
        for (int mi = 0; mi < 4; ++mi)
            af[mi] = *(const bf16x8*)&sA[(waveM + mi * 16 + mrow) * BK + kq];
#pragma unroll
        for (int ni = 0; ni < 4; ++ni)
            bfr[ni] = *(const bf16x8*)&sB[(waveN + ni * 16 + mrow) * BK + kq];

#pragma unroll
        for (int mi = 0; mi < 4; ++mi)
#pragma unroll
            for (int ni = 0; ni < 4; ++ni)
                acc[mi][ni] = __builtin_amdgcn_mfma_f32_16x16x32_bf16(
                    af[mi], bfr[ni], acc[mi][ni], 0, 0, 0);
    }

    // epilogue: C/D layout col=lane&15, row=(lane>>4)*4+reg
    float* Cw = C + (size_t)(blockIdx.y * BM + waveM + (lane >> 4) * 4) * N
                + (size_t)(blockIdx.x * BN + waveN + (lane & 15));
#pragma unroll
    for (int mi = 0; mi < 4; ++mi)
#pragma unroll
        for (int ni = 0; ni < 4; ++ni)
#pragma unroll
            for (int r = 0; r < 4; ++r)
                Cw[(size_t)(mi * 16 + r) * N + ni * 16] = acc[mi][ni][r];
}

// ============ safety-net fallback if ws is too small (slow but correct) ============
__global__ void gemm_naive(const float* __restrict__ x, const int* __restrict__ W,
                           float* __restrict__ out) {
    int n = blockIdx.x * blockDim.x + threadIdx.x;
    int t = blockIdx.y;
    const float* xr = x + (size_t)t * DIN;
    float acc = 0.f;
    for (int k = 0; k < DIN; ++k)
        acc += xr[k] * (float)W[(size_t)k * DOUT + n];
    out[(size_t)t * DOUT + n] = acc;
}

extern "C" void kernel_launch(void* const* d_in, const int* in_sizes, int n_in,
                              void* d_out, int out_size, void* d_ws, size_t ws_size,
                              hipStream_t stream) {
    const float* x = (const float*)d_in[0];
    const int*   W = (const int*)d_in[1];
    float* out = (float*)d_out;

    const size_t xb_elems = (size_t)TOKENS * DIN;           // 64 MB bf16
    const size_t wt_elems = (size_t)DIN * DOUT;             // 32 MB bf16
    const size_t need = (xb_elems + wt_elems) * sizeof(unsigned short);

    if (ws_size < need) {   // should not happen; correctness safety net
        dim3 g(DOUT / 256, TOKENS);
        gemm_naive<<<g, 256, 0, stream>>>(x, W, out);
        return;
    }

    unsigned short* xb = (unsigned short*)d_ws;
    unsigned short* Wt = xb + xb_elems;

    cvt_x_kernel<<<2048, 256, 0, stream>>>(x, xb, (int)(xb_elems / 4));
    cvt_w_kernel<<<dim3(DOUT / 32, DIN / 32), dim3(32, 8), 0, stream>>>(W, Wt);

    dim3 grid(DOUT / BN, TOKENS / BM);   // (32, 64)
    gemm_bt<<<grid, 256, 0, stream>>>(xb, Wt, out);
}